// Round 1
// baseline (172.213 us; speedup 1.0000x reference)
//
#include <hip/hip_runtime.h>
#include <math.h>

// Sizes fixed by the reference problem.
#define B 8
#define F 256
#define L 2048
#define H 8
#define D 32
#define HD 256
// Band half-width: prior(d) = 0.3989*exp(-d^2/2) < 5e-15 for |d|>=8 (std=1),
// so att==0 in fp32 outside |d|<=16. Far keys contribute exactly exp(0)=1,
// which we account for in closed form.
#define W 16

// ---------------------------------------------------------------------------
// Kernel A: projections.  P[b][h][l][d] = sum_f x[b,f,l] * Wm[f, h*D+d] + bm
// grid (L/32, B, 2 {Q,K}), block 256.  Each block: 32 rows (l) x 256 cols (hd).
// X tile staged in LDS (32 KB); W streamed from global (L1/L2 resident, 256 KB).
// ---------------------------------------------------------------------------
__global__ __launch_bounds__(256) void proj_kernel(
    const float* __restrict__ x,                       // [B, F, L]
    const float* __restrict__ Wq, const float* __restrict__ bq,
    const float* __restrict__ Wk, const float* __restrict__ bk,
    float* __restrict__ Qout, float* __restrict__ Kout)  // [B,H,L,D] each
{
    __shared__ float Xs[F * 32];   // 32 KB
    const int l0  = blockIdx.x * 32;
    const int b   = blockIdx.y;
    const int sel = blockIdx.z;
    const float* __restrict__ Wm = sel ? Wk : Wq;
    const float* __restrict__ bm = sel ? bk : bq;
    float* __restrict__ Out = sel ? Kout : Qout;

    const int t = threadIdx.x;
    // Stage X tile: Xs[f*32 + lp] = x[b, f, l0+lp]; coalesced 128B rows.
    #pragma unroll
    for (int i = 0; i < 32; ++i) {
        int idx = i * 256 + t;
        int f = idx >> 5, lp = idx & 31;
        Xs[idx] = x[(b * F + f) * L + l0 + lp];
    }
    __syncthreads();

    const int tl = t >> 5;   // 0..7  -> rows  tl*4 .. tl*4+3
    const int th = t & 31;   // 0..31 -> cols  th*8 .. th*8+7
    float acc[4][8];
    #pragma unroll
    for (int i = 0; i < 4; ++i)
        #pragma unroll
        for (int j = 0; j < 8; ++j) acc[i][j] = 0.f;

    const float* __restrict__ wp = Wm + th * 8;
    #pragma unroll 4
    for (int f = 0; f < F; ++f) {
        // 2 distinct float4 LDS addresses per wave (broadcast) -> conflict-free
        float4 xv = *(const float4*)&Xs[f * 32 + tl * 4];
        float4 w0 = *(const float4*)&wp[f * HD];
        float4 w1 = *(const float4*)&wp[f * HD + 4];
        float xs[4] = {xv.x, xv.y, xv.z, xv.w};
        float ws[8] = {w0.x, w0.y, w0.z, w0.w, w1.x, w1.y, w1.z, w1.w};
        #pragma unroll
        for (int i = 0; i < 4; ++i)
            #pragma unroll
            for (int j = 0; j < 8; ++j)
                acc[i][j] = fmaf(xs[i], ws[j], acc[i][j]);
    }

    #pragma unroll
    for (int j = 0; j < 8; ++j) {
        int hd = th * 8 + j;
        int h = hd >> 5, d = hd & 31;
        float bias = bm[hd];
        #pragma unroll
        for (int i = 0; i < 4; ++i) {
            int l = l0 + tl * 4 + i;
            Out[(((size_t)b * H + h) * L + l) * D + d] = acc[i][j] + bias;
        }
    }
}

// ---------------------------------------------------------------------------
// Kernel B: banded attention + closed-form far terms.
// out_l = (S_l + sum_band expm1(a)*d) / (L + sum_band expm1(a))
// grid (L/256, B*H), block 256; one thread per query row l.
// K band staged in LDS with stride 33 -> bank = (t+c+d) mod 32 -> 2 lanes/bank
// for wave64 (free, per m136).
// ---------------------------------------------------------------------------
__global__ __launch_bounds__(256) void attn_kernel(
    const float* __restrict__ Q,   // [B,H,L,D]
    const float* __restrict__ K,   // [B,H,L,D]
    const float* __restrict__ pmean, const float* __restrict__ pstd,
    float* __restrict__ out)       // [B,L,H]
{
    __shared__ float Ks[(256 + 2 * W) * 33];   // 288*33*4 = 38,016 B
    const int l0 = blockIdx.x * 256;
    const int bh = blockIdx.y;           // b*H + h
    const int b  = bh >> 3, h = bh & 7;
    const int t  = threadIdx.x;

    const float mean = pmean[0];
    const float istd = 1.0f / pstd[0];
    const float cpr  = 0.3989423f * istd;   // matches 1/sqrt(2*3.1415926)

    // Stage K rows [l0-W, l0+256+W)
    const float* __restrict__ Kb = K + (size_t)bh * L * D;
    #pragma unroll
    for (int i = 0; i < (288 * 32) / 256; ++i) {   // 36 iters
        int idx = i * 256 + t;
        int ml = idx >> 5, d = idx & 31;
        int m = l0 - W + ml;
        float v = 0.f;
        if (m >= 0 && m < L) v = Kb[m * D + d];
        Ks[ml * 33 + d] = v;
    }
    __syncthreads();

    const int l = l0 + t;
    const float* __restrict__ qp = Q + ((size_t)bh * L + l) * D;
    float q[32];
    #pragma unroll
    for (int i = 0; i < 8; ++i) {
        float4 v = *(const float4*)&qp[i * 4];
        q[i * 4 + 0] = v.x; q[i * 4 + 1] = v.y;
        q[i * 4 + 2] = v.z; q[i * 4 + 3] = v.w;
    }

    const float scale = 0.17677669529663689f;   // 1/sqrt(D)
    float num = 0.f, den = 0.f;
    #pragma unroll
    for (int dd = -W; dd <= W; ++dd) {
        int m = l + dd;
        if (m < 0 || m >= L) continue;
        const float* kp = &Ks[(t + W + dd) * 33];
        float dot = 0.f;
        #pragma unroll
        for (int d = 0; d < 32; ++d) dot = fmaf(q[d], kp[d], dot);
        float fd = (float)dd;
        float z  = (fd - mean) * istd;
        float pr = cpr * expf(-0.5f * z * z);
        float e  = expm1f(dot * scale * pr);
        num = fmaf(e, fd, num);
        den += e;
    }

    // Exact far-term closed form: S_l = sum_m (m - l) over all m in [0,L)
    float Sl = (float)(L * (L - 1) / 2 - L * l);   // |.| < 2^24, exact fp32
    float res = (Sl + num) / ((float)L + den);
    out[((size_t)b * L + l) * H + h] = res;
}

// ---------------------------------------------------------------------------
extern "C" void kernel_launch(void* const* d_in, const int* in_sizes, int n_in,
                              void* d_out, int out_size, void* d_ws, size_t ws_size,
                              hipStream_t stream) {
    const float* x  = (const float*)d_in[0];   // [B,F,L]
    const float* Wq = (const float*)d_in[1];
    const float* bq = (const float*)d_in[2];
    const float* Wk = (const float*)d_in[3];
    const float* bk = (const float*)d_in[4];
    const float* pm = (const float*)d_in[5];
    const float* ps = (const float*)d_in[6];
    float* out = (float*)d_out;

    float* Qw = (float*)d_ws;                          // 16 MB
    float* Kw = Qw + (size_t)B * H * L * D;            // 16 MB

    proj_kernel<<<dim3(L / 32, B, 2), 256, 0, stream>>>(x, Wq, bq, Wk, bk, Qw, Kw);
    attn_kernel<<<dim3(L / 256, B * H), 256, 0, stream>>>(Qw, Kw, pm, ps, out);
}

// Round 2
// 98.918 us; speedup vs baseline: 1.7410x; 1.7410x over previous
//
#include <hip/hip_runtime.h>
#include <hip/hip_bf16.h>
#include <math.h>

#define B 8
#define F 256
#define L 2048
#define H 8
#define D 32
#define HD 256
#define W 8   // prior(d)=0.3989*exp(-d^2/2) < 5e-15 for |d|>=8 -> att==1.0 exactly in fp32 far field

typedef __attribute__((ext_vector_type(8))) short bf16x8;
typedef __attribute__((ext_vector_type(4))) float f32x4;

__device__ __forceinline__ unsigned short f2bf(float f) {
    union { float f; unsigned u; } v; v.f = f;
    unsigned r = v.u + 0x7FFFu + ((v.u >> 16) & 1u);   // RNE
    return (unsigned short)(r >> 16);
}
__device__ __forceinline__ float bf2f(unsigned u16) {
    union { unsigned u; float f; } v; v.u = u16 << 16;
    return v.f;
}

// ---------------------------------------------------------------------------
// prep: transpose + fp32->bf16 cast.
//   z <  B : x[b,F,L] tile -> Xt[b,L,F]
//   z == B : Wq/Wk [F,HD]  -> Wt[sel,HD,F]   (blockIdx.x<8 only)
// 64x64 tiles through LDS; stride 72 bf16 rows (odd multiple of 16B-ish) keeps
// both phases conflict-light.
// ---------------------------------------------------------------------------
__global__ __launch_bounds__(256) void prep_kernel(
    const float* __restrict__ x, const float* __restrict__ Wq,
    const float* __restrict__ Wk,
    unsigned short* __restrict__ Xt, unsigned short* __restrict__ Wt)
{
    __shared__ unsigned short Ts[64][72];
    const int t = threadIdx.x;
    const int z = blockIdx.z;
    const float* src; unsigned short* dst;
    int srcStride, r0, c0;
    if (z < B) {
        src = x + (size_t)z * F * L;
        dst = Xt + (size_t)z * L * F;
        srcStride = L;
        r0 = blockIdx.y * 64;    // f
        c0 = blockIdx.x * 64;    // l
    } else {
        if (blockIdx.x >= 8) return;
        int sel = blockIdx.x >> 2;
        src = sel ? Wk : Wq;
        dst = Wt + (size_t)sel * HD * F;
        srcStride = HD;
        r0 = blockIdx.y * 64;        // f
        c0 = (blockIdx.x & 3) * 64;  // hd
    }
    #pragma unroll
    for (int rr = 0; rr < 4; ++rr) {
        int r = rr * 16 + (t >> 4);
        int cb = (t & 15) * 4;
        float4 v = *(const float4*)&src[(size_t)(r0 + r) * srcStride + c0 + cb];
        Ts[r][cb + 0] = f2bf(v.x);
        Ts[r][cb + 1] = f2bf(v.y);
        Ts[r][cb + 2] = f2bf(v.z);
        Ts[r][cb + 3] = f2bf(v.w);
    }
    __syncthreads();
    const int c = t >> 2;   // output row (original col)
    #pragma unroll
    for (int half = 0; half < 2; ++half) {
        int ch = (t & 3) + half * 4;   // 16B chunk along f
        unsigned short tmp[8];
        #pragma unroll
        for (int j = 0; j < 8; ++j) tmp[j] = Ts[ch * 8 + j][c];
        *(uint4*)&dst[(size_t)(c0 + c) * F + r0 + ch * 8] = *(const uint4*)tmp;
    }
}

// ---------------------------------------------------------------------------
// gemm: C[l,hd] = sum_f Xt[b,l,f]*Wt[sel,hd,f] + bias -> Q/K bf16 [B,H,L,D]
// block tile 128x128, BK=64 (4 K-chunks), 4 waves of 64x64, 16x16x32 bf16 MFMA.
// LDS row stride 72 bf16 = 144 B = 9*16B (odd multiple of 16B) -> frag
// ds_read_b128 quad-bank = (9*m + quad) mod 8 -> 2-way (free).
// ---------------------------------------------------------------------------
#define ST 72
__global__ __launch_bounds__(256) void gemm_kernel(
    const unsigned short* __restrict__ Xt, const unsigned short* __restrict__ Wt,
    const float* __restrict__ bq, const float* __restrict__ bk,
    unsigned short* __restrict__ Qb, unsigned short* __restrict__ Kb)
{
    __shared__ unsigned short As[128 * ST];
    __shared__ unsigned short Bs[128 * ST];
    const int t   = threadIdx.x;
    const int l0  = blockIdx.x * 128;
    const int n0  = blockIdx.y * 128;
    const int b   = blockIdx.z >> 1;
    const int sel = blockIdx.z & 1;
    const unsigned short* Am = Xt + (size_t)b * L * F;
    const unsigned short* Bm = Wt + (size_t)sel * HD * F;
    const float* bias = sel ? bk : bq;
    unsigned short* Out = sel ? Kb : Qb;

    const int lane = t & 63;
    const int wv   = t >> 6;
    const int wm   = (wv & 1) * 64;
    const int wn   = (wv >> 1) * 64;
    const int lm   = lane & 15;
    const int quad = lane >> 4;

    f32x4 acc[4][4];
    #pragma unroll
    for (int i = 0; i < 4; ++i)
        #pragma unroll
        for (int j = 0; j < 4; ++j) acc[i][j] = (f32x4){0.f, 0.f, 0.f, 0.f};

    for (int kq = 0; kq < 4; ++kq) {
        __syncthreads();
        #pragma unroll
        for (int i = 0; i < 4; ++i) {
            int idx = i * 256 + t;
            int row = idx >> 3, cc = idx & 7;        // row 0..127, 16B chunk 0..7
            uint4 va = *(const uint4*)&Am[(size_t)(l0 + row) * F + kq * 64 + cc * 8];
            *(uint4*)&As[row * ST + cc * 8] = va;
            uint4 vb = *(const uint4*)&Bm[(size_t)(n0 + row) * F + kq * 64 + cc * 8];
            *(uint4*)&Bs[row * ST + cc * 8] = vb;
        }
        __syncthreads();
        #pragma unroll
        for (int ks = 0; ks < 2; ++ks) {
            bf16x8 af[4], bfr[4];
            #pragma unroll
            for (int i = 0; i < 4; ++i)
                af[i] = *(const bf16x8*)&As[(wm + i * 16 + lm) * ST + ks * 32 + quad * 8];
            #pragma unroll
            for (int j = 0; j < 4; ++j)
                bfr[j] = *(const bf16x8*)&Bs[(wn + j * 16 + lm) * ST + ks * 32 + quad * 8];
            #pragma unroll
            for (int i = 0; i < 4; ++i)
                #pragma unroll
                for (int j = 0; j < 4; ++j)
                    acc[i][j] = __builtin_amdgcn_mfma_f32_16x16x32_bf16(
                        af[i], bfr[j], acc[i][j], 0, 0, 0);
        }
    }
    // epilogue: C/D layout col=lane&15, row=quad*4+reg (m89/m91-verified)
    #pragma unroll
    for (int j = 0; j < 4; ++j) {
        int hd = n0 + wn + j * 16 + lm;
        int h = hd >> 5, d = hd & 31;
        float bv = bias[hd];
        unsigned short* op = Out + (((size_t)b * H + h) * L) * D + d;
        #pragma unroll
        for (int i = 0; i < 4; ++i) {
            int l = l0 + wm + i * 16 + quad * 4;
            #pragma unroll
            for (int r = 0; r < 4; ++r)
                op[(size_t)(l + r) * D] = f2bf(acc[i][j][r] + bv);
        }
    }
}

// ---------------------------------------------------------------------------
// attn: banded scores + closed-form far field.
//  out_l = ((Sl - dsum) + sum_band e*d) / ((L - cnt) + sum_band e),  e=exp(a)
// K band staged fp32 in LDS, row stride 36 (144 B = 9*16B) -> ds_read_b128
// dots, 2-way bank aliasing only.  __expf throughout (v_exp_f32).
// ---------------------------------------------------------------------------
__global__ __launch_bounds__(256) void attn_kernel(
    const unsigned short* __restrict__ Qb, const unsigned short* __restrict__ Kb,
    const float* __restrict__ pmean, const float* __restrict__ pstd,
    float* __restrict__ out)
{
    __shared__ float Ks[272 * 36];   // 39168 B
    const int t  = threadIdx.x;
    const int l0 = blockIdx.x * 256;
    const int bh = blockIdx.y;
    const int b = bh >> 3, h = bh & 7;
    const unsigned short* Kbase = Kb + (size_t)bh * L * D;
    const unsigned short* Qbase = Qb + (size_t)bh * L * D;

    const float mean = pmean[0];
    const float istd = 1.0f / pstd[0];
    const float cscale = 0.39894229f * istd * 0.17677670f;  // invsqrt2pi/std * D^-0.5

    #pragma unroll
    for (int i = 0; i < 5; ++i) {
        int cidx = i * 256 + t;                    // 272 rows * 4 chunks = 1088
        if (cidx < 1088) {
            int row = cidx >> 2, cc = cidx & 3;
            int m = l0 - W + row;
            float4 lo = {0.f, 0.f, 0.f, 0.f}, hi = {0.f, 0.f, 0.f, 0.f};
            if (m >= 0 && m < L) {
                uint4 raw = *(const uint4*)&Kbase[(size_t)m * D + cc * 8];
                lo.x = bf2f(raw.x & 0xFFFFu); lo.y = bf2f(raw.x >> 16);
                lo.z = bf2f(raw.y & 0xFFFFu); lo.w = bf2f(raw.y >> 16);
                hi.x = bf2f(raw.z & 0xFFFFu); hi.y = bf2f(raw.z >> 16);
                hi.z = bf2f(raw.w & 0xFFFFu); hi.w = bf2f(raw.w >> 16);
            }
            *(float4*)&Ks[row * 36 + cc * 8]     = lo;
            *(float4*)&Ks[row * 36 + cc * 8 + 4] = hi;
        }
    }

    const int l = l0 + t;
    float q[32];
    #pragma unroll
    for (int cc = 0; cc < 4; ++cc) {
        uint4 raw = *(const uint4*)&Qbase[(size_t)l * D + cc * 8];
        q[cc * 8 + 0] = bf2f(raw.x & 0xFFFFu); q[cc * 8 + 1] = bf2f(raw.x >> 16);
        q[cc * 8 + 2] = bf2f(raw.y & 0xFFFFu); q[cc * 8 + 3] = bf2f(raw.y >> 16);
        q[cc * 8 + 4] = bf2f(raw.z & 0xFFFFu); q[cc * 8 + 5] = bf2f(raw.z >> 16);
        q[cc * 8 + 6] = bf2f(raw.w & 0xFFFFu); q[cc * 8 + 7] = bf2f(raw.w >> 16);
    }
    __syncthreads();

    float num = 0.f, den = 0.f, cnt = 0.f, dsum = 0.f;
    #pragma unroll
    for (int dd = -W; dd <= W; ++dd) {
        int m = l + dd;
        const float* kp = &Ks[(t + W + dd) * 36];
        float dot = 0.f;
        #pragma unroll
        for (int cc = 0; cc < 8; ++cc) {
            float4 kv = *(const float4*)&kp[cc * 4];
            dot = fmaf(q[cc * 4 + 0], kv.x, dot);
            dot = fmaf(q[cc * 4 + 1], kv.y, dot);
            dot = fmaf(q[cc * 4 + 2], kv.z, dot);
            dot = fmaf(q[cc * 4 + 3], kv.w, dot);
        }
        float fd = (float)dd;
        float zz = (fd - mean) * istd;
        float coef = cscale * __expf(-0.5f * zz * zz);
        float e = __expf(dot * coef);
        bool valid = (m >= 0) && (m < L);
        if (valid) { num = fmaf(e, fd, num); den += e; cnt += 1.f; dsum += fd; }
    }
    float Sl = (float)(L * (L - 1) / 2 - L * l);   // exact in fp32 (< 2^22)
    float res = ((Sl - dsum) + num) / (((float)L - cnt) + den);
    out[((size_t)b * L + l) * H + h] = res;
}

// ---------------------------------------------------------------------------
extern "C" void kernel_launch(void* const* d_in, const int* in_sizes, int n_in,
                              void* d_out, int out_size, void* d_ws, size_t ws_size,
                              hipStream_t stream) {
    const float* x  = (const float*)d_in[0];
    const float* Wq = (const float*)d_in[1];
    const float* bq = (const float*)d_in[2];
    const float* Wk = (const float*)d_in[3];
    const float* bk = (const float*)d_in[4];
    const float* pm = (const float*)d_in[5];
    const float* ps = (const float*)d_in[6];
    float* out = (float*)d_out;

    unsigned short* Xt = (unsigned short*)d_ws;                 // B*L*F bf16 = 8 MB
    unsigned short* Wt = Xt + (size_t)B * L * F;                // 2*HD*F bf16 = 256 KB
    unsigned short* Qb = Wt + (size_t)2 * HD * F;               // B*H*L*D bf16 = 8 MB
    unsigned short* Kb = Qb + (size_t)B * H * L * D;            // 8 MB

    prep_kernel<<<dim3(32, 4, B + 1), 256, 0, stream>>>(x, Wq, Wk, Xt, Wt);
    gemm_kernel<<<dim3(16, 2, 16), 256, 0, stream>>>(Xt, Wt, bq, bk, Qb, Kb);
    attn_kernel<<<dim3(8, 64), 256, 0, stream>>>(Qb, Kb, pm, ps, out);
}

// Round 3
// 95.098 us; speedup vs baseline: 1.8109x; 1.0402x over previous
//
#include <hip/hip_runtime.h>
#include <hip/hip_bf16.h>
#include <math.h>

#define B 8
#define F 256
#define L 2048
#define H 8
#define D 32
#define HD 256
#define W 6      // band half-width: prior(6)=6e-9 -> truncation ~1e-6, far field exact
#define HALO 8   // A-tile halo rows (>= W, keeps M=80=5 m-tiles)
#define QST 264  // bf16 row stride for Qs/Ks: 528 B -> b128 reads spread all 32 banks

typedef __attribute__((ext_vector_type(8))) short bf16x8;
typedef __attribute__((ext_vector_type(4))) float f32x4;

__device__ __forceinline__ unsigned short f2bf(float f) {
    union { float f; unsigned u; } v; v.f = f;
    unsigned r = v.u + 0x7FFFu + ((v.u >> 16) & 1u);   // RNE
    return (unsigned short)(r >> 16);
}
__device__ __forceinline__ float bf2f(unsigned u16) {
    union { unsigned u; float f; } v; v.u = u16 << 16;
    return v.f;
}

// ---------------------------------------------------------------------------
// prep: transpose + fp32->bf16 cast (verbatim from round 2, verified).
//   z <  B : x[b,F,L] tile -> Xt[b,L,F]
//   z == B : Wq/Wk [F,HD]  -> Wt[sel,HD,F]
// ---------------------------------------------------------------------------
__global__ __launch_bounds__(256) void prep_kernel(
    const float* __restrict__ x, const float* __restrict__ Wq,
    const float* __restrict__ Wk,
    unsigned short* __restrict__ Xt, unsigned short* __restrict__ Wt)
{
    __shared__ unsigned short Ts[64][72];
    const int t = threadIdx.x;
    const int z = blockIdx.z;
    const float* src; unsigned short* dst;
    int srcStride, r0, c0;
    if (z < B) {
        src = x + (size_t)z * F * L;
        dst = Xt + (size_t)z * L * F;
        srcStride = L;
        r0 = blockIdx.y * 64;    // f
        c0 = blockIdx.x * 64;    // l
    } else {
        if (blockIdx.x >= 8) return;
        int sel = blockIdx.x >> 2;
        src = sel ? Wk : Wq;
        dst = Wt + (size_t)sel * HD * F;
        srcStride = HD;
        r0 = blockIdx.y * 64;        // f
        c0 = (blockIdx.x & 3) * 64;  // hd
    }
    #pragma unroll
    for (int rr = 0; rr < 4; ++rr) {
        int r = rr * 16 + (t >> 4);
        int cb = (t & 15) * 4;
        float4 v = *(const float4*)&src[(size_t)(r0 + r) * srcStride + c0 + cb];
        Ts[r][cb + 0] = f2bf(v.x);
        Ts[r][cb + 1] = f2bf(v.y);
        Ts[r][cb + 2] = f2bf(v.z);
        Ts[r][cb + 3] = f2bf(v.w);
    }
    __syncthreads();
    const int c = t >> 2;
    #pragma unroll
    for (int half = 0; half < 2; ++half) {
        int ch = (t & 3) + half * 4;
        unsigned short tmp[8];
        #pragma unroll
        for (int j = 0; j < 8; ++j) tmp[j] = Ts[ch * 8 + j][c];
        *(uint4*)&dst[(size_t)(c0 + c) * F + r0 + ch * 8] = *(const uint4*)tmp;
    }
}

// ---------------------------------------------------------------------------
// fused: projection GEMM (MFMA, frags direct from global) + banded attention.
// grid (L/64, B) = 256 blocks = 1/CU, 256 threads (4 waves).
// Wave wv covers hd512 = wv*128 .. +127 of [Q 0..255 | K 256..511].
// M = 80 rows (l0-8 .. l0+71); acc[5] only, A-frags cached (160 VGPR).
// Results land in LDS Qs/Ks[80][QST] bf16; one barrier; banded softmax.
// ---------------------------------------------------------------------------
__global__ __launch_bounds__(256, 1) void fused_kernel(
    const unsigned short* __restrict__ Xt, const unsigned short* __restrict__ Wt,
    const float* __restrict__ bq, const float* __restrict__ bk,
    const float* __restrict__ pmean, const float* __restrict__ pstd,
    float* __restrict__ out)
{
    __shared__ unsigned short Qs[80 * QST];   // 42,240 B
    __shared__ unsigned short Ks[80 * QST];   // 42,240 B
    const int t    = threadIdx.x;
    const int l0   = blockIdx.x * 64;
    const int b    = blockIdx.y;
    const int lane = t & 63, wv = t >> 6;
    const int lm   = lane & 15, quad = lane >> 4;

    // Signed offset: b=0,l0=0 under-runs Xt by 4 KB -> covered by ws pad.
    const unsigned short* Arow = Xt + ((long)b * L + (long)l0 - HALO) * F;

    // A fragments: rows mt*16+lm (0..79), k = ks*32 + quad*8.
    bf16x8 af[5][8];
    #pragma unroll
    for (int mt = 0; mt < 5; ++mt)
        #pragma unroll
        for (int ks = 0; ks < 8; ++ks)
            af[mt][ks] = *(const bf16x8*)&Arow[(long)(mt * 16 + lm) * F + ks * 32 + quad * 8];

    #pragma unroll
    for (int nt = 0; nt < 8; ++nt) {
        const int hdq = wv * 128 + nt * 16 + lm;   // 0..511
        const int sel = hdq >> 8;                  // wave-uniform (tiles don't straddle 256)
        const int hd  = hdq & 255;
        const unsigned short* Brow = Wt + ((size_t)sel * HD + hd) * F;
        f32x4 acc[5];
        #pragma unroll
        for (int mt = 0; mt < 5; ++mt) acc[mt] = (f32x4){0.f, 0.f, 0.f, 0.f};
        #pragma unroll
        for (int ks = 0; ks < 8; ++ks) {
            bf16x8 bfr = *(const bf16x8*)&Brow[ks * 32 + quad * 8];
            #pragma unroll
            for (int mt = 0; mt < 5; ++mt)
                acc[mt] = __builtin_amdgcn_mfma_f32_16x16x32_bf16(
                    af[mt][ks], bfr, acc[mt], 0, 0, 0);
        }
        // epilogue: C/D layout col=lane&15 (=hd), row=quad*4+r (m89-verified)
        float bv = sel ? bk[hd] : bq[hd];
        unsigned short* dst = sel ? Ks : Qs;
        #pragma unroll
        for (int mt = 0; mt < 5; ++mt)
            #pragma unroll
            for (int r = 0; r < 4; ++r)
                dst[(mt * 16 + quad * 4 + r) * QST + hd] = f2bf(acc[mt][r] + bv);
    }
    __syncthreads();

    const float mean = pmean[0];
    const float istd = 1.0f / pstd[0];
    const float cs   = 0.39894229f * istd * 0.17677670f;  // invsqrt2pi/std * D^-0.5
    float coef[2 * W + 1];
    #pragma unroll
    for (int j = 0; j <= 2 * W; ++j) {
        float z = ((float)(j - W) - mean) * istd;
        coef[j] = cs * __expf(-0.5f * z * z);
    }

    #pragma unroll
    for (int rep = 0; rep < 2; ++rep) {
        const int o  = rep * 256 + t;        // 512 outputs: 64 l x 8 h
        const int lp = o & 63, h = o >> 6;
        const int l  = l0 + lp;
        const int row = lp + HALO;
        const unsigned short* qp = &Qs[row * QST + h * 32];
        float q[32];
        #pragma unroll
        for (int c = 0; c < 4; ++c) {
            uint4 raw = *(const uint4*)&qp[c * 8];
            unsigned u[4] = {raw.x, raw.y, raw.z, raw.w};
            #pragma unroll
            for (int p = 0; p < 4; ++p) {
                q[c * 8 + p * 2]     = bf2f(u[p] & 0xFFFFu);
                q[c * 8 + p * 2 + 1] = bf2f(u[p] >> 16);
            }
        }
        float num = 0.f, den = 0.f, cnt = 0.f, dsum = 0.f;
        #pragma unroll
        for (int j = 0; j <= 2 * W; ++j) {
            const int dd = j - W;
            const int m  = l + dd;
            const unsigned short* kp = &Ks[(row + dd) * QST + h * 32];
            float dot = 0.f;
            #pragma unroll
            for (int c = 0; c < 4; ++c) {
                uint4 raw = *(const uint4*)&kp[c * 8];
                unsigned u[4] = {raw.x, raw.y, raw.z, raw.w};
                #pragma unroll
                for (int p = 0; p < 4; ++p) {
                    dot = fmaf(q[c * 8 + p * 2],     bf2f(u[p] & 0xFFFFu), dot);
                    dot = fmaf(q[c * 8 + p * 2 + 1], bf2f(u[p] >> 16),     dot);
                }
            }
            float e = __expf(dot * coef[j]);
            if (m >= 0 && m < L) {
                num = fmaf(e, (float)dd, num);
                den += e; cnt += 1.f; dsum += (float)dd;
            }
        }
        // far field: every out-of-band key contributes exp(0)=1 exactly
        float Sl = (float)(L * (L - 1) / 2 - L * l);   // exact in fp32
        out[((size_t)b * L + l) * H + h] =
            ((Sl - dsum) + num) / (((float)L - cnt) + den);
    }
}

// ---------------------------------------------------------------------------
extern "C" void kernel_launch(void* const* d_in, const int* in_sizes, int n_in,
                              void* d_out, int out_size, void* d_ws, size_t ws_size,
                              hipStream_t stream) {
    const float* x  = (const float*)d_in[0];
    const float* Wq = (const float*)d_in[1];
    const float* bq = (const float*)d_in[2];
    const float* Wk = (const float*)d_in[3];
    const float* bk = (const float*)d_in[4];
    const float* pm = (const float*)d_in[5];
    const float* ps = (const float*)d_in[6];
    float* out = (float*)d_out;

    // [64 KB pad (absorbs halo under-run)] [Xt 8 MB] [Wt 256 KB]
    unsigned short* Xt = (unsigned short*)d_ws + 32768;
    unsigned short* Wt = Xt + (size_t)B * L * F;

    prep_kernel<<<dim3(32, 4, B + 1), 256, 0, stream>>>(x, Wq, Wk, Xt, Wt);
    fused_kernel<<<dim3(L / 64, B), 256, 0, stream>>>(Xt, Wt, bq, bk, pm, ps, out);
}

// Round 4
// 94.923 us; speedup vs baseline: 1.8142x; 1.0018x over previous
//
#include <hip/hip_runtime.h>
#include <hip/hip_bf16.h>
#include <math.h>

#define B 8
#define F 256
#define L 2048
#define H 8
#define D 32
#define HD 256
#define W 6      // prior(6)=6e-9 -> band truncation ~1e-6; far field exact (exp(0)=1)
#define HALO 8   // halo rows each side of the 64-l tile -> M=80 rows
#define KST 264  // bf16 row stride (528 B): b128 wave reads evenly spread 32 banks
#define QSTF 132 // fp32 row stride (528 B) for Qs

typedef __attribute__((ext_vector_type(8))) short bf16x8;
typedef __attribute__((ext_vector_type(4))) float f32x4;

__device__ __forceinline__ unsigned short f2bf_fast(float f) {
    union { float f; unsigned u; } v; v.f = f;
    return (unsigned short)((v.u + 0x8000u) >> 16);   // round-to-nearest, ties away
}
__device__ __forceinline__ float bf2f(unsigned u16) {
    union { unsigned u; float f; } v; v.u = u16 << 16;
    return v.f;
}

// ---------------------------------------------------------------------------
// prep_w: W[F,HD] fp32 -> Wt[sel,HD,F] bf16 (transpose+cast; verified pattern).
// grid (8,4): sel = x>>2, hd-tile = x&3, f-tile = y.  32 blocks, ~0.5 MB traffic.
// ---------------------------------------------------------------------------
__global__ __launch_bounds__(256) void prep_w_kernel(
    const float* __restrict__ Wq, const float* __restrict__ Wk,
    unsigned short* __restrict__ Wt)
{
    __shared__ unsigned short Ts[64][72];
    const int t   = threadIdx.x;
    const int sel = blockIdx.x >> 2;
    const int c0  = (blockIdx.x & 3) * 64;   // hd
    const int r0  = blockIdx.y * 64;         // f
    const float* __restrict__ src = sel ? Wk : Wq;
    unsigned short* __restrict__ dst = Wt + (size_t)sel * HD * F;

    #pragma unroll
    for (int rr = 0; rr < 4; ++rr) {
        int r = rr * 16 + (t >> 4);
        int cb = (t & 15) * 4;
        float4 v = *(const float4*)&src[(size_t)(r0 + r) * HD + c0 + cb];
        Ts[r][cb + 0] = f2bf_fast(v.x);
        Ts[r][cb + 1] = f2bf_fast(v.y);
        Ts[r][cb + 2] = f2bf_fast(v.z);
        Ts[r][cb + 3] = f2bf_fast(v.w);
    }
    __syncthreads();
    const int c = t >> 2;
    #pragma unroll
    for (int half = 0; half < 2; ++half) {
        int ch = (t & 3) + half * 4;
        unsigned short tmp[8];
        #pragma unroll
        for (int j = 0; j < 8; ++j) tmp[j] = Ts[ch * 8 + j][c];
        *(uint4*)&dst[(size_t)(c0 + c) * F + r0 + ch * 8] = *(const uint4*)tmp;
    }
}

// ---------------------------------------------------------------------------
// fused: X-transpose (global->LDS bf16) + projection MFMA + banded attention.
// grid (32, 8) = 256 blocks = 1/CU, 256 threads.
//   phase 0: Xs[80][KST] bf16 <- x[b, :, l0-8 .. l0+71] (clamped at edges;
//            clamped halo rows are masked out downstream, never consumed)
//   phase 1: af[5][8] frags from Xs (regs) | barrier | 8 nt-tiles of MFMA with
//            B-frags streamed from L2-hot Wt; epilogue -> Qs fp32 / Ks bf16.
//            Qs aliases Xs (both 42,240 B) — legal after the af-load barrier.
//   phase 2: banded softmax, W=6, far field closed-form.
// ---------------------------------------------------------------------------
__global__ __launch_bounds__(256, 1) void fused_kernel(
    const float* __restrict__ x, const unsigned short* __restrict__ Wt,
    const float* __restrict__ bq, const float* __restrict__ bk,
    const float* __restrict__ pmean, const float* __restrict__ pstd,
    float* __restrict__ out)
{
    __shared__ uint4 smem4[5280];                                // 84,480 B
    unsigned short* Xs = (unsigned short*)smem4;                 // [80][264] bf16
    float*          Qs = (float*)smem4;                          // [80][132] fp32 (alias)
    unsigned short* Ks = (unsigned short*)(smem4 + 2640);        // [80][264] bf16

    const int t    = threadIdx.x;
    const int l0   = blockIdx.x * 64;
    const int b    = blockIdx.y;
    const int lane = t & 63, wv = t >> 6;
    const int lm   = lane & 15, quad = lane >> 4;

    // ---- phase 0: stage Xs (transpose + cast) ----
    const float* __restrict__ xb = x + (size_t)b * F * L;
    #pragma unroll
    for (int i = 0; i < 20; ++i) {
        int idx = i * 256 + t;          // 5120 tasks: 80 l-rows x 64 f-chunks
        int lp  = idx % 80;
        int fg  = idx / 80;
        int m   = l0 - HALO + lp;
        m = min(max(m, 0), L - 1);      // edge clamp; clamped rows masked later
        unsigned p0, p1;
        {
            float v0 = xb[(size_t)(4 * fg + 0) * L + m];
            float v1 = xb[(size_t)(4 * fg + 1) * L + m];
            p0 = ((__float_as_uint(v0) + 0x8000u) >> 16) |
                 (((__float_as_uint(v1) + 0x8000u) >> 16) << 16);
            float v2 = xb[(size_t)(4 * fg + 2) * L + m];
            float v3 = xb[(size_t)(4 * fg + 3) * L + m];
            p1 = ((__float_as_uint(v2) + 0x8000u) >> 16) |
                 (((__float_as_uint(v3) + 0x8000u) >> 16) << 16);
        }
        uint2 pk; pk.x = p0; pk.y = p1;
        *(uint2*)&Xs[lp * KST + 4 * fg] = pk;
    }
    __syncthreads();

    // ---- A fragments into registers (160 VGPR), then Xs is dead ----
    bf16x8 af[5][8];
    #pragma unroll
    for (int mt = 0; mt < 5; ++mt)
        #pragma unroll
        for (int ks = 0; ks < 8; ++ks)
            af[mt][ks] = *(const bf16x8*)&Xs[(mt * 16 + lm) * KST + ks * 32 + quad * 8];
    __syncthreads();   // all af reads drained before Qs overwrites Xs

    // ---- phase 1: MFMA nt-tiles ----
    #pragma unroll
    for (int nt = 0; nt < 8; ++nt) {
        const int hdq = wv * 128 + nt * 16 + lm;   // 0..511
        const int sel = hdq >> 8;                  // wave-uniform
        const int hd  = hdq & 255;
        const unsigned short* Brow = Wt + ((size_t)sel * HD + hd) * F;
        f32x4 acc[5];
        #pragma unroll
        for (int mt = 0; mt < 5; ++mt) acc[mt] = (f32x4){0.f, 0.f, 0.f, 0.f};
        #pragma unroll
        for (int ks = 0; ks < 8; ++ks) {
            bf16x8 bfr = *(const bf16x8*)&Brow[ks * 32 + quad * 8];
            #pragma unroll
            for (int mt = 0; mt < 5; ++mt)
                acc[mt] = __builtin_amdgcn_mfma_f32_16x16x32_bf16(
                    af[mt][ks], bfr, acc[mt], 0, 0, 0);
        }
        // C/D layout: col=lane&15 (=hd), row=quad*4+r (m89/m91-verified)
        float bv = sel ? bk[hd] : bq[hd];
        if (sel == 0) {
            #pragma unroll
            for (int mt = 0; mt < 5; ++mt)
                #pragma unroll
                for (int r = 0; r < 4; ++r)
                    Qs[(mt * 16 + quad * 4 + r) * QSTF + hd] = acc[mt][r] + bv;
        } else {
            #pragma unroll
            for (int mt = 0; mt < 5; ++mt)
                #pragma unroll
                for (int r = 0; r < 4; ++r)
                    Ks[(mt * 16 + quad * 4 + r) * KST + hd] = f2bf_fast(acc[mt][r] + bv);
        }
    }
    __syncthreads();

    // ---- phase 2: banded attention ----
    const float mean = pmean[0];
    const float istd = 1.0f / pstd[0];
    const float cs   = 0.39894229f * istd * 0.17677670f;  // invsqrt2pi/std * D^-0.5
    float coef[2 * W + 1];
    #pragma unroll
    for (int j = 0; j <= 2 * W; ++j) {
        float z = ((float)(j - W) - mean) * istd;
        coef[j] = cs * __expf(-0.5f * z * z);
    }

    #pragma unroll
    for (int rep = 0; rep < 2; ++rep) {
        const int o   = rep * 256 + t;       // 512 outputs: 64 l x 8 h
        const int lp  = o & 63, h = o >> 6;
        const int l   = l0 + lp;
        const int row = lp + HALO;
        const float* qp = &Qs[row * QSTF + h * 32];
        float q[32];
        #pragma unroll
        for (int c = 0; c < 8; ++c) {
            float4 v = *(const float4*)&qp[c * 4];
            q[c * 4 + 0] = v.x; q[c * 4 + 1] = v.y;
            q[c * 4 + 2] = v.z; q[c * 4 + 3] = v.w;
        }
        float num = 0.f, den = 0.f, cnt = 0.f, dsum = 0.f;
        #pragma unroll
        for (int j = 0; j <= 2 * W; ++j) {
            const int dd = j - W;
            const int m  = l + dd;
            const unsigned short* kp = &Ks[(row + dd) * KST + h * 32];
            float dot = 0.f;
            #pragma unroll
            for (int c = 0; c < 4; ++c) {
                uint4 raw = *(const uint4*)&kp[c * 8];
                unsigned u[4] = {raw.x, raw.y, raw.z, raw.w};
                #pragma unroll
                for (int p = 0; p < 4; ++p) {
                    dot = fmaf(q[c * 8 + p * 2],     bf2f(u[p] & 0xFFFFu), dot);
                    dot = fmaf(q[c * 8 + p * 2 + 1], bf2f(u[p] >> 16),     dot);
                }
            }
            float e = __expf(dot * coef[j]);
            if (m >= 0 && m < L) {
                num = fmaf(e, (float)dd, num);
                den += e; cnt += 1.f; dsum += (float)dd;
            }
        }
        // far field: every out-of-band valid key contributes exp(0)=1 exactly
        float Sl = (float)(L * (L - 1) / 2 - L * l);   // exact in fp32
        out[((size_t)b * L + l) * H + h] =
            ((Sl - dsum) + num) / (((float)L - cnt) + den);
    }
}

// ---------------------------------------------------------------------------
extern "C" void kernel_launch(void* const* d_in, const int* in_sizes, int n_in,
                              void* d_out, int out_size, void* d_ws, size_t ws_size,
                              hipStream_t stream) {
    const float* x  = (const float*)d_in[0];
    const float* Wq = (const float*)d_in[1];
    const float* bq = (const float*)d_in[2];
    const float* Wk = (const float*)d_in[3];
    const float* bk = (const float*)d_in[4];
    const float* pm = (const float*)d_in[5];
    const float* ps = (const float*)d_in[6];
    float* out = (float*)d_out;

    unsigned short* Wt = (unsigned short*)d_ws;    // 2*HD*F bf16 = 256 KB

    prep_w_kernel<<<dim3(8, 4), 256, 0, stream>>>(Wq, Wk, Wt);
    fused_kernel<<<dim3(L / 64, B), 256, 0, stream>>>(x, Wt, bq, bk, pm, ps, out);
}